// Round 11
// baseline (345.428 us; speedup 1.0000x reference)
//
#include <hip/hip_runtime.h>
#include <hip/hip_bf16.h>
#include <stdint.h>

#define N_ROWS 8192
#define DIM    1024
#define BM 128
#define BN 128
#define BKF 128            // fp8 bytes of K per tile (= one MFMA K)
#define NT (DIM / BKF)     // 8 K-slices per C-tile
#define TILES_PB 8         // B-tiles per block (F-amortization)

typedef float   f32x4  __attribute__((ext_vector_type(4)));
typedef int     i32x4  __attribute__((ext_vector_type(4)));
typedef int     i32x8  __attribute__((ext_vector_type(8)));

// 16-lane (DPP row) sum via v_add_f32 + row_ror — no LDS traffic.
__device__ __forceinline__ float row_sum16(float x) {
    x += __int_as_float(__builtin_amdgcn_update_dpp(
            0, __float_as_int(x), 0x128 /*row_ror:8*/, 0xf, 0xf, true));
    x += __int_as_float(__builtin_amdgcn_update_dpp(
            0, __float_as_int(x), 0x124 /*row_ror:4*/, 0xf, 0xf, true));
    x += __int_as_float(__builtin_amdgcn_update_dpp(
            0, __float_as_int(x), 0x122 /*row_ror:2*/, 0xf, 0xf, true));
    x += __int_as_float(__builtin_amdgcn_update_dpp(
            0, __float_as_int(x), 0x121 /*row_ror:1*/, 0xf, 0xf, true));
    return x;
}

// ---------------------------------------------------------------------------
// Kernel 1: L2-normalize + fp8 cast + diagonal + S init.
// Wave-per-row (zero barriers, zero LDS).  UNCHANGED from R10.
// ---------------------------------------------------------------------------
__global__ __launch_bounds__(256) void nrm_kernel(
    const float* __restrict__ img, const float* __restrict__ txt,
    uint8_t* __restrict__ img_f8, uint8_t* __restrict__ txt_f8,
    float* __restrict__ diag, float* __restrict__ S)
{
    const int t    = threadIdx.x;
    const int lane = t & 63;
    const int wv   = t >> 6;
    const int row  = blockIdx.x * 4 + wv;

    const float4* ip = (const float4*)(img + (size_t)row * DIM);
    const float4* tp = (const float4*)(txt + (size_t)row * DIM);

    float4 a[4], b[4];
    float sa = 0.f, sb = 0.f, dp = 0.f;
#pragma unroll
    for (int j = 0; j < 4; ++j) {
        a[j] = ip[lane + 64 * j];
        b[j] = tp[lane + 64 * j];
        sa += a[j].x * a[j].x + a[j].y * a[j].y + a[j].z * a[j].z + a[j].w * a[j].w;
        sb += b[j].x * b[j].x + b[j].y * b[j].y + b[j].z * b[j].z + b[j].w * b[j].w;
        dp += a[j].x * b[j].x + a[j].y * b[j].y + a[j].z * b[j].z + a[j].w * b[j].w;
    }
#pragma unroll
    for (int d = 1; d < 64; d <<= 1) {
        sa += __shfl_xor(sa, d, 64);
        sb += __shfl_xor(sb, d, 64);
        dp += __shfl_xor(dp, d, 64);
    }

    const float ia = 1.0f / fmaxf(sqrtf(sa), 1e-12f);
    const float ib = 1.0f / fmaxf(sqrtf(sb), 1e-12f);

#pragma unroll
    for (int j = 0; j < 4; ++j) {
        int ra = 0, rb = 0;
        ra = __builtin_amdgcn_cvt_pk_fp8_f32(a[j].x * ia, a[j].y * ia, ra, false);
        ra = __builtin_amdgcn_cvt_pk_fp8_f32(a[j].z * ia, a[j].w * ia, ra, true);
        rb = __builtin_amdgcn_cvt_pk_fp8_f32(b[j].x * ib, b[j].y * ib, rb, false);
        rb = __builtin_amdgcn_cvt_pk_fp8_f32(b[j].z * ib, b[j].w * ib, rb, true);
        ((int*)(img_f8 + (size_t)row * DIM))[lane + 64 * j] = ra;
        ((int*)(txt_f8 + (size_t)row * DIM))[lane + 64 * j] = rb;
    }

    if (lane == 0) {
        diag[row] = dp * ia * ib;   // normalized diagonal (linearity)
        S[row] = 0.0f;
    }
}

// ---------------------------------------------------------------------------
// Kernel 2: 128x128 MX-fp8 GEMM, multi-tile blocks — UNROLLED K-SLICE LOOP.
//   R10 residual: ~80 VALU/step/wave of addressing in a latency-bound step.
//   Key identity: buffer parity = ks&1 (tile*8 even) => with the 8-slice
//   inner loop UNROLLED, read/write buffer selection, staging K-offsets
//   (ks*128, folds into the 13-bit global inst offset), and ds_read
//   immediates (rbuf + mi*2048, fits imm16) are ALL compile-time.  A staging
//   pointers are loop-invariant (same panel for all 64 steps); B pointers
//   advance once per tile.  Removes ptr-advance adds, wrap cndmasks, XOR
//   toggles (~25-30 VALU/step).  Skeleton per step byte-equivalent to R8/R10:
//   { stage(v+1) ; 16 ds_read ; 16 MFMA ; [epilogue @ks==7] ; vmcnt(0) ;
//   s_barrier } — dbuf 2x32KiB, XOR chunk swizzle, DPP row-sum epilogue.
// ---------------------------------------------------------------------------
__global__ __launch_bounds__(256) void sim_lse_kernel(
    const uint8_t* __restrict__ A, const uint8_t* __restrict__ B,
    float* __restrict__ S)
{
    __shared__ __align__(16) uint8_t smem[2 * 2 * BM * BKF];   // 64 KiB

    const int t     = threadIdx.x;       // 0..255
    const int lane  = t & 63;
    const int w     = t >> 6;            // wave 0..3
    const int waveM = w >> 1;            // 2x2 wave grid, 64x64 each
    const int waveN = w & 1;
    const int lr    = lane & 15;
    const int q     = lane >> 4;
    const int swz   = lr & 7;

    const int rowA0 = blockIdx.y * BM;                    // A panel (0..63)
    const uint8_t* Ablk = A + (size_t)rowA0 * DIM;
    const uint8_t* Bgrp = B + (size_t)blockIdx.x * TILES_PB * BN * DIM;

    const uint32_t lo_off = (uint32_t)(((2 * q) ^ swz) * 16);

    // ---- staging pointers: A loop-invariant; B advances once per tile -----
    const uint8_t* pA[4];
    const uint8_t* pB[4];
    uint32_t ldsA[4], ldsB[4];
#pragma unroll
    for (int is = 0; is < 4; ++is) {
        const int c   = is * 256 + t;        // 16B chunk id, 0..1023
        const int row = c >> 3;              // 0..127
        const int col = (c & 7) ^ (row & 7); // pre-swizzled source chunk
        pA[is] = Ablk + (size_t)row * DIM + col * 16;
        pB[is] = Bgrp + (size_t)row * DIM + col * 16;
        ldsA[is] = (uint32_t)c * 16;
        ldsB[is] = 16384u + (uint32_t)c * 16;
    }

    // stage slice koff (compile-time) of current A/B tile into buffer wbuf
    auto stageAB = [&](uint32_t wbuf, int koff) {
#pragma unroll
        for (int is = 0; is < 4; ++is) {
            __builtin_amdgcn_global_load_lds(
                (const __attribute__((address_space(1))) void*)(pA[is] + koff),
                (__attribute__((address_space(3))) void*)&smem[wbuf + ldsA[is]],
                16, 0, 0);
            __builtin_amdgcn_global_load_lds(
                (const __attribute__((address_space(1))) void*)(pB[is] + koff),
                (__attribute__((address_space(3))) void*)&smem[wbuf + ldsB[is]],
                16, 0, 0);
        }
    };

    // ---- per-lane ds_read base addresses (constant; imm carries the rest) -
    const uint32_t adrA  = (uint32_t)((waveM * 64 + lr) * BKF) + lo_off;
    const uint32_t adrAh = (uint32_t)((waveM * 64 + lr) * BKF) + (lo_off ^ 16u);
    const uint32_t adrB  = (uint32_t)((waveN * 64 + lr) * BKF) + lo_off;
    const uint32_t adrBh = (uint32_t)((waveN * 64 + lr) * BKF) + (lo_off ^ 16u);

    f32x4 acc[4][4] = {};

    // ---- prologue: stage slice 0 into buffer 0, drain once ----------------
    stageAB(0u, 0);
    asm volatile("s_waitcnt vmcnt(0)" ::: "memory");
    __builtin_amdgcn_s_barrier();

    const float L2E = 1.44269504088896f;
    const int rowbase = rowA0 + waveM * 64;

    // ---- main loop: tiles x (8 k-slices UNROLLED) -------------------------
#pragma unroll 1
    for (int tile = 0; tile < TILES_PB; ++tile) {
#pragma unroll
        for (int ks = 0; ks < NT; ++ks) {
            const uint32_t rbuf = (uint32_t)((ks & 1) << 15);   // compile-time
            const uint32_t wbuf = rbuf ^ 32768u;

            // stage next virtual step (issue, don't wait)
            if (ks < NT - 1) {
                stageAB(wbuf, (ks + 1) * BKF);
            } else if (tile < TILES_PB - 1) {
#pragma unroll
                for (int is = 0; is < 4; ++is) pB[is] += BN * DIM;  // once/tile
                stageAB(wbuf, 0);
            }

            // fragments: reg = per-lane base; imm = rbuf + frag*2048 (+16K B)
            i32x8 af[4], bfr[4];
#pragma unroll
            for (int mi = 0; mi < 4; ++mi) {
                i32x4 lo = *(const i32x4*)&smem[(size_t)adrA  + rbuf + mi * 2048];
                i32x4 hi = *(const i32x4*)&smem[(size_t)adrAh + rbuf + mi * 2048];
                af[mi] = __builtin_shufflevector(lo, hi, 0, 1, 2, 3, 4, 5, 6, 7);
            }
#pragma unroll
            for (int ni = 0; ni < 4; ++ni) {
                i32x4 lo = *(const i32x4*)&smem[(size_t)adrB  + rbuf + 16384u + ni * 2048];
                i32x4 hi = *(const i32x4*)&smem[(size_t)adrBh + rbuf + 16384u + ni * 2048];
                bfr[ni] = __builtin_shufflevector(lo, hi, 0, 1, 2, 3, 4, 5, 6, 7);
            }
#pragma unroll
            for (int mi = 0; mi < 4; ++mi)
#pragma unroll
                for (int ni = 0; ni < 4; ++ni)
                    acc[mi][ni] = __builtin_amdgcn_mfma_scale_f32_16x16x128_f8f6f4(
                        af[mi], bfr[ni], acc[mi][ni],
                        0 /*fmtA=fp8*/, 0 /*fmtB=fp8*/,
                        0, 127 /*scaleA=1.0*/, 0, 127 /*scaleB=1.0*/);

            // tile finished: fused epilogue (overlaps in-flight staging)
            if (ks == NT - 1) {
#pragma unroll
                for (int mi = 0; mi < 4; ++mi) {
                    float p0 = 0.f, p1 = 0.f, p2 = 0.f, p3 = 0.f;
#pragma unroll
                    for (int ni = 0; ni < 4; ++ni) {
                        p0 += exp2f(acc[mi][ni].x * L2E - L2E);
                        p1 += exp2f(acc[mi][ni].y * L2E - L2E);
                        p2 += exp2f(acc[mi][ni].z * L2E - L2E);
                        p3 += exp2f(acc[mi][ni].w * L2E - L2E);
                        acc[mi][ni] = (f32x4){0.f, 0.f, 0.f, 0.f};
                    }
                    p0 = row_sum16(p0); p1 = row_sum16(p1);
                    p2 = row_sum16(p2); p3 = row_sum16(p3);
                    if ((lane & 15) == 0) {
                        float* dst = &S[rowbase + mi * 16 + (lane >> 4) * 4];
                        atomicAdd(dst + 0, p0); atomicAdd(dst + 1, p1);
                        atomicAdd(dst + 2, p2); atomicAdd(dst + 3, p3);
                    }
                }
            }

            asm volatile("s_waitcnt vmcnt(0)" ::: "memory");
            __builtin_amdgcn_s_barrier();
        }
    }
}

// ---------------------------------------------------------------------------
// Kernel 3: out = mean(log(S_i) - diag_i)   UNCHANGED
// ---------------------------------------------------------------------------
__global__ __launch_bounds__(1024) void fin_kernel(
    const float* __restrict__ S, const float* __restrict__ diag,
    float* __restrict__ out)
{
    const int t = threadIdx.x;
    float s = 0.f;
    for (int i = t; i < N_ROWS; i += 1024) s += logf(S[i]) - diag[i];
#pragma unroll
    for (int d = 1; d < 64; d <<= 1) s += __shfl_xor(s, d, 64);
    __shared__ float red[16];
    if ((t & 63) == 0) red[t >> 6] = s;
    __syncthreads();
    if (t == 0) {
        float tot = 0.f;
#pragma unroll
        for (int i = 0; i < 16; ++i) tot += red[i];
        out[0] = tot * (1.0f / N_ROWS);
    }
}

// ---------------------------------------------------------------------------
extern "C" void kernel_launch(void* const* d_in, const int* in_sizes, int n_in,
                              void* d_out, int out_size, void* d_ws, size_t ws_size,
                              hipStream_t stream)
{
    const float* img = (const float*)d_in[0];
    const float* txt = (const float*)d_in[1];
    float* out = (float*)d_out;

    char* ws = (char*)d_ws;
    uint8_t* img_f8 = (uint8_t*)ws;                                  // 8 MiB
    uint8_t* txt_f8 = (uint8_t*)(ws + (size_t)N_ROWS * DIM);         // 8 MiB
    float*   S      = (float*)(ws + (size_t)N_ROWS * DIM * 2);       // 32 KiB
    float*   diag   = S + N_ROWS;                                    // 32 KiB

    nrm_kernel<<<N_ROWS / 4, 256, 0, stream>>>(img, txt, img_f8, txt_f8,
                                               diag, S);
    dim3 grid(N_ROWS / BN / TILES_PB, N_ROWS / BM);   // 8 groups x 64 panels
    sim_lse_kernel<<<grid, 256, 0, stream>>>(img_f8, txt_f8, S);
    fin_kernel<<<1, 1024, 0, stream>>>(S, diag, out);
}

// Round 12
// 192.488 us; speedup vs baseline: 1.7945x; 1.7945x over previous
//
#include <hip/hip_runtime.h>
#include <hip/hip_bf16.h>
#include <stdint.h>

#define N_ROWS 8192
#define DIM    1024
#define BM 128
#define BN 128
#define BKF 128            // fp8 bytes of K per tile (= one MFMA K)
#define NT (DIM / BKF)     // 8 K-slices per C-tile
#define TILES_PB 8         // B-tiles per block (F-amortization)
#define VSTEPS (NT * TILES_PB)   // 64 virtual K-steps per block

typedef float   f32x4  __attribute__((ext_vector_type(4)));
typedef int     i32x4  __attribute__((ext_vector_type(4)));
typedef int     i32x8  __attribute__((ext_vector_type(8)));

// 16-lane (DPP row) sum via v_add_f32 + row_ror — no LDS traffic.
__device__ __forceinline__ float row_sum16(float x) {
    x += __int_as_float(__builtin_amdgcn_update_dpp(
            0, __float_as_int(x), 0x128 /*row_ror:8*/, 0xf, 0xf, true));
    x += __int_as_float(__builtin_amdgcn_update_dpp(
            0, __float_as_int(x), 0x124 /*row_ror:4*/, 0xf, 0xf, true));
    x += __int_as_float(__builtin_amdgcn_update_dpp(
            0, __float_as_int(x), 0x122 /*row_ror:2*/, 0xf, 0xf, true));
    x += __int_as_float(__builtin_amdgcn_update_dpp(
            0, __float_as_int(x), 0x121 /*row_ror:1*/, 0xf, 0xf, true));
    return x;
}

// ---------------------------------------------------------------------------
// Kernel 1: L2-normalize + fp8 cast + diagonal + S init.
// Wave-per-row (zero barriers, zero LDS).  UNCHANGED from R10.
// ---------------------------------------------------------------------------
__global__ __launch_bounds__(256) void nrm_kernel(
    const float* __restrict__ img, const float* __restrict__ txt,
    uint8_t* __restrict__ img_f8, uint8_t* __restrict__ txt_f8,
    float* __restrict__ diag, float* __restrict__ S)
{
    const int t    = threadIdx.x;
    const int lane = t & 63;
    const int wv   = t >> 6;
    const int row  = blockIdx.x * 4 + wv;

    const float4* ip = (const float4*)(img + (size_t)row * DIM);
    const float4* tp = (const float4*)(txt + (size_t)row * DIM);

    float4 a[4], b[4];
    float sa = 0.f, sb = 0.f, dp = 0.f;
#pragma unroll
    for (int j = 0; j < 4; ++j) {
        a[j] = ip[lane + 64 * j];
        b[j] = tp[lane + 64 * j];
        sa += a[j].x * a[j].x + a[j].y * a[j].y + a[j].z * a[j].z + a[j].w * a[j].w;
        sb += b[j].x * b[j].x + b[j].y * b[j].y + b[j].z * b[j].z + b[j].w * b[j].w;
        dp += a[j].x * b[j].x + a[j].y * b[j].y + a[j].z * b[j].z + a[j].w * b[j].w;
    }
#pragma unroll
    for (int d = 1; d < 64; d <<= 1) {
        sa += __shfl_xor(sa, d, 64);
        sb += __shfl_xor(sb, d, 64);
        dp += __shfl_xor(dp, d, 64);
    }

    const float ia = 1.0f / fmaxf(sqrtf(sa), 1e-12f);
    const float ib = 1.0f / fmaxf(sqrtf(sb), 1e-12f);

#pragma unroll
    for (int j = 0; j < 4; ++j) {
        int ra = 0, rb = 0;
        ra = __builtin_amdgcn_cvt_pk_fp8_f32(a[j].x * ia, a[j].y * ia, ra, false);
        ra = __builtin_amdgcn_cvt_pk_fp8_f32(a[j].z * ia, a[j].w * ia, ra, true);
        rb = __builtin_amdgcn_cvt_pk_fp8_f32(b[j].x * ib, b[j].y * ib, rb, false);
        rb = __builtin_amdgcn_cvt_pk_fp8_f32(b[j].z * ib, b[j].w * ib, rb, true);
        ((int*)(img_f8 + (size_t)row * DIM))[lane + 64 * j] = ra;
        ((int*)(txt_f8 + (size_t)row * DIM))[lane + 64 * j] = rb;
    }

    if (lane == 0) {
        diag[row] = dp * ia * ib;   // normalized diagonal (linearity)
        S[row] = 0.0f;
    }
}

// ---------------------------------------------------------------------------
// Kernel 2: 128x128 MX-fp8 GEMM, multi-tile blocks — R10 base + MANUAL 2-STEP
// body.  R11's full 8x unroll exploded live ranges (VGPR 256, 28 MB spill);
// the entire compile-time-buffer benefit needs only 2x: parity = v&1.
//   pair p handles v=2p (read buf0 / stage buf1) then v=2p+1 (read buf1 /
//   stage buf0).  Derived simplifications: odd sub-step pointer wrap can
//   never fire (wrap needs v%8==6, even) -> unconditional +128; even
//   sub-step wrap collapses to (p&3)==3; epilogue (v&7==7) lands only in the
//   odd sub-step at (p&3)==3.  Everything else byte-identical to R10:
//   512 blocks (8 B-groups x 64 A-panels), dist-1 dbuf 64 KiB, XOR chunk
//   swizzle, incremental uniform-delta staging pointers, shufflevector
//   frags, per-tile DPP row-sum epilogue, atomicAdd into S.
//   #pragma unroll 1 pinned on the pair loop (R11 lesson).
// ---------------------------------------------------------------------------
__global__ __launch_bounds__(256) void sim_lse_kernel(
    const uint8_t* __restrict__ A, const uint8_t* __restrict__ B,
    float* __restrict__ S)
{
    __shared__ __align__(16) uint8_t smem[2 * 2 * BM * BKF];   // 64 KiB

    const int t     = threadIdx.x;       // 0..255
    const int lane  = t & 63;
    const int w     = t >> 6;            // wave 0..3
    const int waveM = w >> 1;            // 2x2 wave grid, 64x64 each
    const int waveN = w & 1;
    const int lr    = lane & 15;
    const int q     = lane >> 4;
    const int swz   = lr & 7;

    const int rowA0 = blockIdx.y * BM;                    // A panel (0..63)
    const uint8_t* Ablk = A + (size_t)rowA0 * DIM;
    const uint8_t* Bgrp = B + (size_t)blockIdx.x * TILES_PB * BN * DIM;

    const uint32_t lo_off = (uint32_t)(((2 * q) ^ swz) * 16);

    // ---- staging pointers: init ONCE, then uniform-delta advance ----------
    const uint8_t* pA[4];
    const uint8_t* pB[4];
    uint32_t ldsA[4], ldsB[4];
#pragma unroll
    for (int is = 0; is < 4; ++is) {
        const int c   = is * 256 + t;        // 16B chunk id, 0..1023
        const int row = c >> 3;              // 0..127
        const int col = (c & 7) ^ (row & 7); // pre-swizzled source chunk
        pA[is] = Ablk + (size_t)row * DIM + col * 16;
        pB[is] = Bgrp + (size_t)row * DIM + col * 16;
        ldsA[is] = (uint32_t)c * 16;
        ldsB[is] = 16384u + (uint32_t)c * 16;
    }

    auto stage_inc = [&](uint32_t ldsbase) {
#pragma unroll
        for (int is = 0; is < 4; ++is) {
            __builtin_amdgcn_global_load_lds(
                (const __attribute__((address_space(1))) void*)pA[is],
                (__attribute__((address_space(3))) void*)&smem[ldsbase + ldsA[is]],
                16, 0, 0);
            __builtin_amdgcn_global_load_lds(
                (const __attribute__((address_space(1))) void*)pB[is],
                (__attribute__((address_space(3))) void*)&smem[ldsbase + ldsB[is]],
                16, 0, 0);
        }
    };

    // ---- per-lane ds_read base addresses (constant; imm carries the rest) -
    const uint32_t adrA  = (uint32_t)((waveM * 64 + lr) * BKF) + lo_off;
    const uint32_t adrAh = (uint32_t)((waveM * 64 + lr) * BKF) + (lo_off ^ 16u);
    const uint32_t adrB  = 16384u + (uint32_t)((waveN * 64 + lr) * BKF) + lo_off;
    const uint32_t adrBh = 16384u + (uint32_t)((waveN * 64 + lr) * BKF) + (lo_off ^ 16u);

    f32x4 acc[4][4] = {};

    // ---- prologue: stage v=0 into buf0, advance to v=1 data, drain once ---
    stage_inc(0u);
#pragma unroll
    for (int is = 0; is < 4; ++is) { pA[is] += 128; pB[is] += 128; }
    asm volatile("s_waitcnt vmcnt(0)" ::: "memory");
    __builtin_amdgcn_s_barrier();

    const float L2E = 1.44269504088896f;
    const int rowbase = rowA0 + waveM * 64;

    // compute-on-current-buffer helper; RBUF is compile-time (0 or 32768)
    auto compute = [&](uint32_t RBUF) {
        i32x8 af[4], bfr[4];
#pragma unroll
        for (int mi = 0; mi < 4; ++mi) {
            i32x4 lo = *(const i32x4*)&smem[adrA  + RBUF + mi * 2048];
            i32x4 hi = *(const i32x4*)&smem[adrAh + RBUF + mi * 2048];
            af[mi] = __builtin_shufflevector(lo, hi, 0, 1, 2, 3, 4, 5, 6, 7);
        }
#pragma unroll
        for (int ni = 0; ni < 4; ++ni) {
            i32x4 lo = *(const i32x4*)&smem[adrB  + RBUF + ni * 2048];
            i32x4 hi = *(const i32x4*)&smem[adrBh + RBUF + ni * 2048];
            bfr[ni] = __builtin_shufflevector(lo, hi, 0, 1, 2, 3, 4, 5, 6, 7);
        }
#pragma unroll
        for (int mi = 0; mi < 4; ++mi)
#pragma unroll
            for (int ni = 0; ni < 4; ++ni)
                acc[mi][ni] = __builtin_amdgcn_mfma_scale_f32_16x16x128_f8f6f4(
                    af[mi], bfr[ni], acc[mi][ni],
                    0 /*fmtA=fp8*/, 0 /*fmtB=fp8*/,
                    0, 127 /*scaleA=1.0*/, 0, 127 /*scaleB=1.0*/);
    };

    // ---- main loop: 32 pairs of steps; buffers compile-time per sub-step --
#pragma unroll 1
    for (int p = 0; p < VSTEPS / 2; ++p) {
        // ===== sub-step A: v = 2p (even). read buf0, stage buf1 ===========
        stage_inc(32768u);                         // stage v+1 (always: 2p<63)
        {
            // advance to v+2 data; wrap iff (2p+1)%8==7  <=>  (p&3)==3
            const bool wrap = (p & 3) == 3;
            const int dA = wrap ? -(BKF * (NT - 1)) : BKF;              // -896 | +128
            const int dB = wrap ? (BN * DIM - BKF * (NT - 1)) : BKF;    // +130176 | +128
#pragma unroll
            for (int is = 0; is < 4; ++is) { pA[is] += dA; pB[is] += dB; }
        }
        compute(0u);
        // even v can't be ks==7: no epilogue here
        asm volatile("s_waitcnt vmcnt(0)" ::: "memory");
        __builtin_amdgcn_s_barrier();

        // ===== sub-step B: v = 2p+1 (odd). read buf1, stage buf0 ==========
        if (p < VSTEPS / 2 - 1) {
            stage_inc(0u);                         // stage v+1
            // advance to v+2 data; wrap impossible ((2p+2)%8 != 7): +128
#pragma unroll
            for (int is = 0; is < 4; ++is) { pA[is] += 128; pB[is] += 128; }
        }
        compute(32768u);

        if ((p & 3) == 3) {   // v&7==7: tile finished -> fused epilogue
#pragma unroll
            for (int mi = 0; mi < 4; ++mi) {
                float p0 = 0.f, p1 = 0.f, p2 = 0.f, p3 = 0.f;
#pragma unroll
                for (int ni = 0; ni < 4; ++ni) {
                    p0 += exp2f(acc[mi][ni].x * L2E - L2E);
                    p1 += exp2f(acc[mi][ni].y * L2E - L2E);
                    p2 += exp2f(acc[mi][ni].z * L2E - L2E);
                    p3 += exp2f(acc[mi][ni].w * L2E - L2E);
                    acc[mi][ni] = (f32x4){0.f, 0.f, 0.f, 0.f};
                }
                p0 = row_sum16(p0); p1 = row_sum16(p1);
                p2 = row_sum16(p2); p3 = row_sum16(p3);
                if ((lane & 15) == 0) {
                    float* dst = &S[rowbase + mi * 16 + (lane >> 4) * 4];
                    atomicAdd(dst + 0, p0); atomicAdd(dst + 1, p1);
                    atomicAdd(dst + 2, p2); atomicAdd(dst + 3, p3);
                }
            }
        }

        asm volatile("s_waitcnt vmcnt(0)" ::: "memory");
        __builtin_amdgcn_s_barrier();
    }
}

// ---------------------------------------------------------------------------
// Kernel 3: out = mean(log(S_i) - diag_i)   UNCHANGED
// ---------------------------------------------------------------------------
__global__ __launch_bounds__(1024) void fin_kernel(
    const float* __restrict__ S, const float* __restrict__ diag,
    float* __restrict__ out)
{
    const int t = threadIdx.x;
    float s = 0.f;
    for (int i = t; i < N_ROWS; i += 1024) s += logf(S[i]) - diag[i];
#pragma unroll
    for (int d = 1; d < 64; d <<= 1) s += __shfl_xor(s, d, 64);
    __shared__ float red[16];
    if ((t & 63) == 0) red[t >> 6] = s;
    __syncthreads();
    if (t == 0) {
        float tot = 0.f;
#pragma unroll
        for (int i = 0; i < 16; ++i) tot += red[i];
        out[0] = tot * (1.0f / N_ROWS);
    }
}

// ---------------------------------------------------------------------------
extern "C" void kernel_launch(void* const* d_in, const int* in_sizes, int n_in,
                              void* d_out, int out_size, void* d_ws, size_t ws_size,
                              hipStream_t stream)
{
    const float* img = (const float*)d_in[0];
    const float* txt = (const float*)d_in[1];
    float* out = (float*)d_out;

    char* ws = (char*)d_ws;
    uint8_t* img_f8 = (uint8_t*)ws;                                  // 8 MiB
    uint8_t* txt_f8 = (uint8_t*)(ws + (size_t)N_ROWS * DIM);         // 8 MiB
    float*   S      = (float*)(ws + (size_t)N_ROWS * DIM * 2);       // 32 KiB
    float*   diag   = S + N_ROWS;                                    // 32 KiB

    nrm_kernel<<<N_ROWS / 4, 256, 0, stream>>>(img, txt, img_f8, txt_f8,
                                               diag, S);
    dim3 grid(N_ROWS / BN / TILES_PB, N_ROWS / BM);   // 8 groups x 64 panels
    sim_lse_kernel<<<grid, 256, 0, stream>>>(img_f8, txt_f8, S);
    fin_kernel<<<1, 1024, 0, stream>>>(S, diag, out);
}

// Round 13
// 179.287 us; speedup vs baseline: 1.9267x; 1.0736x over previous
//
#include <hip/hip_runtime.h>
#include <hip/hip_bf16.h>
#include <stdint.h>

#define N_ROWS 8192
#define DIM    1024
#define BM 128
#define BN 128
#define BKF 128            // fp8 bytes of K per tile (= one MFMA K)
#define NT (DIM / BKF)     // 8 K-slices per C-tile
#define TILES_PB 8         // B-tiles per block (F-amortization)
#define VSTEPS (NT * TILES_PB)   // 64 virtual K-steps per block

typedef float   f32x4  __attribute__((ext_vector_type(4)));
typedef int     i32x4  __attribute__((ext_vector_type(4)));
typedef int     i32x8  __attribute__((ext_vector_type(8)));

// 16-lane (DPP row) sum via v_add_f32 + row_ror — no LDS traffic.
__device__ __forceinline__ float row_sum16(float x) {
    x += __int_as_float(__builtin_amdgcn_update_dpp(
            0, __float_as_int(x), 0x128 /*row_ror:8*/, 0xf, 0xf, true));
    x += __int_as_float(__builtin_amdgcn_update_dpp(
            0, __float_as_int(x), 0x124 /*row_ror:4*/, 0xf, 0xf, true));
    x += __int_as_float(__builtin_amdgcn_update_dpp(
            0, __float_as_int(x), 0x122 /*row_ror:2*/, 0xf, 0xf, true));
    x += __int_as_float(__builtin_amdgcn_update_dpp(
            0, __float_as_int(x), 0x121 /*row_ror:1*/, 0xf, 0xf, true));
    return x;
}

// ---------------------------------------------------------------------------
// Kernel 1: L2-normalize + fp8 cast + diagonal + S init.
// Wave-per-row (zero barriers, zero LDS).  UNCHANGED.
// ---------------------------------------------------------------------------
__global__ __launch_bounds__(256) void nrm_kernel(
    const float* __restrict__ img, const float* __restrict__ txt,
    uint8_t* __restrict__ img_f8, uint8_t* __restrict__ txt_f8,
    float* __restrict__ diag, float* __restrict__ S)
{
    const int t    = threadIdx.x;
    const int lane = t & 63;
    const int wv   = t >> 6;
    const int row  = blockIdx.x * 4 + wv;

    const float4* ip = (const float4*)(img + (size_t)row * DIM);
    const float4* tp = (const float4*)(txt + (size_t)row * DIM);

    float4 a[4], b[4];
    float sa = 0.f, sb = 0.f, dp = 0.f;
#pragma unroll
    for (int j = 0; j < 4; ++j) {
        a[j] = ip[lane + 64 * j];
        b[j] = tp[lane + 64 * j];
        sa += a[j].x * a[j].x + a[j].y * a[j].y + a[j].z * a[j].z + a[j].w * a[j].w;
        sb += b[j].x * b[j].x + b[j].y * b[j].y + b[j].z * b[j].z + b[j].w * b[j].w;
        dp += a[j].x * b[j].x + a[j].y * b[j].y + a[j].z * b[j].z + a[j].w * b[j].w;
    }
#pragma unroll
    for (int d = 1; d < 64; d <<= 1) {
        sa += __shfl_xor(sa, d, 64);
        sb += __shfl_xor(sb, d, 64);
        dp += __shfl_xor(dp, d, 64);
    }

    const float ia = 1.0f / fmaxf(sqrtf(sa), 1e-12f);
    const float ib = 1.0f / fmaxf(sqrtf(sb), 1e-12f);

#pragma unroll
    for (int j = 0; j < 4; ++j) {
        int ra = 0, rb = 0;
        ra = __builtin_amdgcn_cvt_pk_fp8_f32(a[j].x * ia, a[j].y * ia, ra, false);
        ra = __builtin_amdgcn_cvt_pk_fp8_f32(a[j].z * ia, a[j].w * ia, ra, true);
        rb = __builtin_amdgcn_cvt_pk_fp8_f32(b[j].x * ib, b[j].y * ib, rb, false);
        rb = __builtin_amdgcn_cvt_pk_fp8_f32(b[j].z * ib, b[j].w * ib, rb, true);
        ((int*)(img_f8 + (size_t)row * DIM))[lane + 64 * j] = ra;
        ((int*)(txt_f8 + (size_t)row * DIM))[lane + 64 * j] = rb;
    }

    if (lane == 0) {
        diag[row] = dp * ia * ib;   // normalized diagonal (linearity)
        S[row] = 0.0f;
    }
}

// ---------------------------------------------------------------------------
// Kernel 2: 128x128 MX-fp8 GEMM — R12 skeleton + 8 WAVES (TLP 2x).
//   Occupancy sat at ~20% (2 compute-waves/SIMD) for all 12 rounds; every
//   pipe <=40% busy => step is latency-exposed, and the untouched lever is
//   inter-wave TLP.  512 threads, 4M x 2N wave grid, wave tile 32x64:
//   acc[2][4] (32 VGPR), 8 MFMA + 12 ds_read_b128 per wave-step, 4 staging
//   chunks/thread.  2 blocks/CU (64 KiB LDS) -> 16 waves/CU = 4 waves/SIMD:
//   while one wave waits at vmcnt/barrier, three others issue.
//   Plain __launch_bounds__(512) — no min-wave arg (R1 lesson); demand est.
//   ~115 VGPR: compiler should land <=128 for the full 4/SIMD cap.
//   Everything else byte-identical to R12: 2-step pair loop (compile-time
//   buffer parity), dist-1 dbuf, XOR chunk swizzle, uniform-delta staging
//   pointers, shufflevector frags, per-tile DPP row-sum epilogue @ (p&3)==3,
//   atomicAdd into S.
// ---------------------------------------------------------------------------
__global__ __launch_bounds__(512) void sim_lse_kernel(
    const uint8_t* __restrict__ A, const uint8_t* __restrict__ B,
    float* __restrict__ S)
{
    __shared__ __align__(16) uint8_t smem[2 * 2 * BM * BKF];   // 64 KiB

    const int t     = threadIdx.x;       // 0..511
    const int lane  = t & 63;
    const int w     = t >> 6;            // wave 0..7
    const int waveM = w >> 1;            // 0..3 : 32 rows each
    const int waveN = w & 1;             // 0..1 : 64 cols each
    const int lr    = lane & 15;
    const int q     = lane >> 4;
    const int swz   = lr & 7;

    const int rowA0 = blockIdx.y * BM;                    // A panel (0..63)
    const uint8_t* Ablk = A + (size_t)rowA0 * DIM;
    const uint8_t* Bgrp = B + (size_t)blockIdx.x * TILES_PB * BN * DIM;

    const uint32_t lo_off = (uint32_t)(((2 * q) ^ swz) * 16);

    // ---- staging: 512 threads x (2 A + 2 B) chunks; uniform-delta advance -
    const uint8_t* pA[2];
    const uint8_t* pB[2];
    uint32_t ldsA[2], ldsB[2];
#pragma unroll
    for (int is = 0; is < 2; ++is) {
        const int c   = is * 512 + t;        // 16B chunk id, 0..1023
        const int row = c >> 3;              // 0..127
        const int col = (c & 7) ^ (row & 7); // pre-swizzled source chunk
        pA[is] = Ablk + (size_t)row * DIM + col * 16;
        pB[is] = Bgrp + (size_t)row * DIM + col * 16;
        ldsA[is] = (uint32_t)c * 16;
        ldsB[is] = 16384u + (uint32_t)c * 16;
    }

    auto stage_inc = [&](uint32_t ldsbase) {
#pragma unroll
        for (int is = 0; is < 2; ++is) {
            __builtin_amdgcn_global_load_lds(
                (const __attribute__((address_space(1))) void*)pA[is],
                (__attribute__((address_space(3))) void*)&smem[ldsbase + ldsA[is]],
                16, 0, 0);
            __builtin_amdgcn_global_load_lds(
                (const __attribute__((address_space(1))) void*)pB[is],
                (__attribute__((address_space(3))) void*)&smem[ldsbase + ldsB[is]],
                16, 0, 0);
        }
    };

    // ---- per-lane ds_read base addresses (constant; imm carries frag idx) -
    const uint32_t adrA  = (uint32_t)((waveM * 32 + lr) * BKF) + lo_off;
    const uint32_t adrAh = (uint32_t)((waveM * 32 + lr) * BKF) + (lo_off ^ 16u);
    const uint32_t adrB  = 16384u + (uint32_t)((waveN * 64 + lr) * BKF) + lo_off;
    const uint32_t adrBh = 16384u + (uint32_t)((waveN * 64 + lr) * BKF) + (lo_off ^ 16u);

    f32x4 acc[2][4] = {};

    // ---- prologue: stage v=0 into buf0, advance to v=1 data, drain once ---
    stage_inc(0u);
#pragma unroll
    for (int is = 0; is < 2; ++is) { pA[is] += 128; pB[is] += 128; }
    asm volatile("s_waitcnt vmcnt(0)" ::: "memory");
    __builtin_amdgcn_s_barrier();

    const float L2E = 1.44269504088896f;
    const int rowbase = rowA0 + waveM * 32;

    // compute-on-current-buffer helper; RBUF is compile-time (0 or 32768)
    auto compute = [&](uint32_t RBUF) {
        i32x8 af[2], bfr[4];
#pragma unroll
        for (int mi = 0; mi < 2; ++mi) {
            i32x4 lo = *(const i32x4*)&smem[adrA  + RBUF + mi * 2048];
            i32x4 hi = *(const i32x4*)&smem[adrAh + RBUF + mi * 2048];
            af[mi] = __builtin_shufflevector(lo, hi, 0, 1, 2, 3, 4, 5, 6, 7);
        }
#pragma unroll
        for (int ni = 0; ni < 4; ++ni) {
            i32x4 lo = *(const i32x4*)&smem[adrB  + RBUF + ni * 2048];
            i32x4 hi = *(const i32x4*)&smem[adrBh + RBUF + ni * 2048];
            bfr[ni] = __builtin_shufflevector(lo, hi, 0, 1, 2, 3, 4, 5, 6, 7);
        }
#pragma unroll
        for (int mi = 0; mi < 2; ++mi)
#pragma unroll
            for (int ni = 0; ni < 4; ++ni)
                acc[mi][ni] = __builtin_amdgcn_mfma_scale_f32_16x16x128_f8f6f4(
                    af[mi], bfr[ni], acc[mi][ni],
                    0 /*fmtA=fp8*/, 0 /*fmtB=fp8*/,
                    0, 127 /*scaleA=1.0*/, 0, 127 /*scaleB=1.0*/);
    };

    // ---- main loop: 32 pairs of steps; buffers compile-time per sub-step --
#pragma unroll 1
    for (int p = 0; p < VSTEPS / 2; ++p) {
        // ===== sub-step A: v = 2p (even). read buf0, stage buf1 ===========
        stage_inc(32768u);                         // stage v+1 (always: 2p<63)
        {
            // advance to v+2 data; wrap iff (2p+1)%8==7  <=>  (p&3)==3
            const bool wrap = (p & 3) == 3;
            const int dA = wrap ? -(BKF * (NT - 1)) : BKF;              // -896 | +128
            const int dB = wrap ? (BN * DIM - BKF * (NT - 1)) : BKF;    // +130176 | +128
#pragma unroll
            for (int is = 0; is < 2; ++is) { pA[is] += dA; pB[is] += dB; }
        }
        compute(0u);
        // even v can't be ks==7: no epilogue here
        asm volatile("s_waitcnt vmcnt(0)" ::: "memory");
        __builtin_amdgcn_s_barrier();

        // ===== sub-step B: v = 2p+1 (odd). read buf1, stage buf0 ==========
        if (p < VSTEPS / 2 - 1) {
            stage_inc(0u);                         // stage v+1
            // advance to v+2 data; wrap impossible ((2p+2)%8 != 7): +128
#pragma unroll
            for (int is = 0; is < 2; ++is) { pA[is] += 128; pB[is] += 128; }
        }
        compute(32768u);

        if ((p & 3) == 3) {   // v&7==7: tile finished -> fused epilogue
#pragma unroll
            for (int mi = 0; mi < 2; ++mi) {
                float p0 = 0.f, p1 = 0.f, p2 = 0.f, p3 = 0.f;
#pragma unroll
                for (int ni = 0; ni < 4; ++ni) {
                    p0 += exp2f(acc[mi][ni].x * L2E - L2E);
                    p1 += exp2f(acc[mi][ni].y * L2E - L2E);
                    p2 += exp2f(acc[mi][ni].z * L2E - L2E);
                    p3 += exp2f(acc[mi][ni].w * L2E - L2E);
                    acc[mi][ni] = (f32x4){0.f, 0.f, 0.f, 0.f};
                }
                p0 = row_sum16(p0); p1 = row_sum16(p1);
                p2 = row_sum16(p2); p3 = row_sum16(p3);
                if ((lane & 15) == 0) {
                    float* dst = &S[rowbase + mi * 16 + (lane >> 4) * 4];
                    atomicAdd(dst + 0, p0); atomicAdd(dst + 1, p1);
                    atomicAdd(dst + 2, p2); atomicAdd(dst + 3, p3);
                }
            }
        }

        asm volatile("s_waitcnt vmcnt(0)" ::: "memory");
        __builtin_amdgcn_s_barrier();
    }
}

// ---------------------------------------------------------------------------
// Kernel 3: out = mean(log(S_i) - diag_i)   UNCHANGED
// ---------------------------------------------------------------------------
__global__ __launch_bounds__(1024) void fin_kernel(
    const float* __restrict__ S, const float* __restrict__ diag,
    float* __restrict__ out)
{
    const int t = threadIdx.x;
    float s = 0.f;
    for (int i = t; i < N_ROWS; i += 1024) s += logf(S[i]) - diag[i];
#pragma unroll
    for (int d = 1; d < 64; d <<= 1) s += __shfl_xor(s, d, 64);
    __shared__ float red[16];
    if ((t & 63) == 0) red[t >> 6] = s;
    __syncthreads();
    if (t == 0) {
        float tot = 0.f;
#pragma unroll
        for (int i = 0; i < 16; ++i) tot += red[i];
        out[0] = tot * (1.0f / N_ROWS);
    }
}

// ---------------------------------------------------------------------------
extern "C" void kernel_launch(void* const* d_in, const int* in_sizes, int n_in,
                              void* d_out, int out_size, void* d_ws, size_t ws_size,
                              hipStream_t stream)
{
    const float* img = (const float*)d_in[0];
    const float* txt = (const float*)d_in[1];
    float* out = (float*)d_out;

    char* ws = (char*)d_ws;
    uint8_t* img_f8 = (uint8_t*)ws;                                  // 8 MiB
    uint8_t* txt_f8 = (uint8_t*)(ws + (size_t)N_ROWS * DIM);         // 8 MiB
    float*   S      = (float*)(ws + (size_t)N_ROWS * DIM * 2);       // 32 KiB
    float*   diag   = S + N_ROWS;                                    // 32 KiB

    nrm_kernel<<<N_ROWS / 4, 256, 0, stream>>>(img, txt, img_f8, txt_f8,
                                               diag, S);
    dim3 grid(N_ROWS / BN / TILES_PB, N_ROWS / BM);   // 8 groups x 64 panels
    sim_lse_kernel<<<grid, 512, 0, stream>>>(img_f8, txt_f8, S);
    fin_kernel<<<1, 1024, 0, stream>>>(S, diag, out);
}